// Round 1
// 389.056 us; speedup vs baseline: 1.0057x; 1.0057x over previous
//
#include <hip/hip_runtime.h>

// FFM forward, MI355X (gfx950).
// dense[4096,13] f32, sparse[4096,26] i32, w0[1], w[260013,1], v[260013,39,8].
// out[4096,1].
//
// v row = 39*8 = 312 floats = 78 float4 (row stride 1248 B, 16B-aligned).
// Block = 320 threads (5 waves) handles RPB=4 batch rows; thread t owns
// (row r = t/80, float4 slot s = t%80), slots 78,79 are padding (contribute 0).
// Gathers are dwordx4, 1 KB per wave-instruction, 26 independent loads in
// flight per thread. Element e = 4s+i has k = (4s+i)&7, so even slots hold
// k=0..3 and odd slots k=4..7: S_k reduces with parity-preserving shuffles.
// 16-lane shuffle groups never straddle a row (80 = 5*16) or a wave (16|64).

constexpr int V_DEPTH  = 10000;
constexpr int N_DENSE  = 13;
constexpr int N_SPARSE = 26;
constexpr int FIELD    = 39;          // 13 + 26
constexpr int K        = 8;
constexpr int FK       = FIELD * K;   // 312
constexpr int SLOT     = FK / 4;      // 78 float4 per v row
constexpr int SLOTP    = 80;          // padded to 5 * 16
constexpr int RPB      = 4;           // batch rows per block
constexpr int BLOCK    = RPB * SLOTP; // 320 threads = 5 waves
constexpr int NGRP     = SLOTP / 16;  // 5 sixteen-lane groups per row

__global__ __launch_bounds__(BLOCK) void ffm_fwd_kernel(
    const float* __restrict__ dense,
    const int*   __restrict__ sparse,
    const float* __restrict__ w0,
    const float* __restrict__ w,
    const float* __restrict__ v,
    float*       __restrict__ out,
    int batch)
{
    const int b0 = blockIdx.x * RPB;
    const int t  = threadIdx.x;

    __shared__ int   s_idx[RPB][N_SPARSE];
    __shared__ float s_wg[RPB][N_SPARSE];
    __shared__ float s_dense[RPB][N_DENSE];
    __shared__ float s_wd[N_DENSE];
    __shared__ float s_S[RPB][NGRP][2][4];   // per-group parity partials of S_k
    __shared__ float s_sq[RPB][NGRP];        // per-group sum of squares

    // ---- setup: disjoint thread ranges ----
    if (t < RPB * N_SPARSE) {                                  // t 0..103
        const int r = t / N_SPARSE, j = t - r * N_SPARSE;
        const int row = b0 + r;
        int id = N_DENSE;
        float wg = 0.0f;
        if (row < batch) {
            id = sparse[row * N_SPARSE + j] + N_DENSE + j * V_DEPTH;
            wg = w[id];
        }
        s_idx[r][j] = id;
        s_wg[r][j]  = wg;
    } else if (t >= 128 && t < 128 + RPB * N_DENSE) {          // t 128..179
        const int u = t - 128;
        const int r = u / N_DENSE, d = u - r * N_DENSE;
        const int row = b0 + r;
        s_dense[r][d] = (row < batch) ? dense[row * N_DENSE + d] : 0.0f;
    } else if (t >= 192 && t < 192 + N_DENSE) {                // t 192..204
        s_wd[t - 192] = w[t - 192];
    }
    __syncthreads();

    const int r = t / SLOTP;           // compile-time div
    const int s = t - r * SLOTP;

    // ---- per-element accumulation (same per-element order as verified
    //      kernel: dense FMAs d=0..12 first, then gathers j=0..25) ----
    float ax = 0.0f, ay = 0.0f, az = 0.0f, aw = 0.0f;
    if (s < SLOT) {
        const float4* __restrict__ v4 = reinterpret_cast<const float4*>(v);
        #pragma unroll
        for (int d = 0; d < N_DENSE; ++d) {
            const float4 g = v4[d * SLOT + s];      // 16 KB block, L2-hot
            const float sd = s_dense[r][d];
            ax = fmaf(sd, g.x, ax); ay = fmaf(sd, g.y, ay);
            az = fmaf(sd, g.z, az); aw = fmaf(sd, g.w, aw);
        }
        #pragma unroll
        for (int j = 0; j < N_SPARSE; ++j) {
            const float4 g = v4[s_idx[r][j] * SLOT + s];  // gathered, HBM/L3
            ax += g.x; ay += g.y; az += g.z; aw += g.w;
        }
    }

    // ---- reductions inside 16-lane groups ----
    float sq = ax * ax + ay * ay + az * az + aw * aw;
    #pragma unroll
    for (int off = 8; off >= 1; off >>= 1) sq += __shfl_xor(sq, off, 64);

    float sx = ax, sy = ay, sz = az, sw = aw;
    #pragma unroll
    for (int off = 8; off >= 2; off >>= 1) {       // parity-preserving
        sx += __shfl_xor(sx, off, 64);
        sy += __shfl_xor(sy, off, 64);
        sz += __shfl_xor(sz, off, 64);
        sw += __shfl_xor(sw, off, 64);
    }

    const int grp = s >> 4;
    const int sl  = s & 15;
    if (sl < 2) {
        // sl==0: even slots -> S[0..3] partial; sl==1: odd slots -> S[4..7]
        s_S[r][grp][sl][0] = sx;
        s_S[r][grp][sl][1] = sy;
        s_S[r][grp][sl][2] = sz;
        s_S[r][grp][sl][3] = sw;
        if (sl == 0) s_sq[r][grp] = sq;
    }
    __syncthreads();

    // ---- finalize: one thread per batch row ----
    if (t < RPB && (b0 + t) < batch) {
        const int rr = t;
        float S[K];
        #pragma unroll
        for (int k = 0; k < K; ++k) S[k] = 0.0f;
        float sumsq = 0.0f;
        #pragma unroll
        for (int g = 0; g < NGRP; ++g) {
            #pragma unroll
            for (int i = 0; i < 4; ++i) {
                S[i]     += s_S[rr][g][0][i];
                S[4 + i] += s_S[rr][g][1][i];
            }
            sumsq += s_sq[rr][g];
        }
        float ssum = 0.0f;
        #pragma unroll
        for (int k = 0; k < K; ++k) ssum += S[k] * S[k];

        float linear = w0[0];
        #pragma unroll
        for (int j = 0; j < N_SPARSE; ++j) linear += s_wg[rr][j];
        #pragma unroll
        for (int d = 0; d < N_DENSE; ++d)  linear += s_dense[rr][d] * s_wd[d];

        out[b0 + rr] = linear + 0.5f * (ssum - sumsq);
    }
}

extern "C" void kernel_launch(void* const* d_in, const int* in_sizes, int n_in,
                              void* d_out, int out_size, void* d_ws, size_t ws_size,
                              hipStream_t stream) {
    const float* dense  = (const float*)d_in[0];
    const int*   sparse = (const int*)  d_in[1];
    const float* w0     = (const float*)d_in[2];
    const float* w      = (const float*)d_in[3];
    const float* v      = (const float*)d_in[4];
    float* out = (float*)d_out;

    const int batch = out_size;                 // 4096
    const int grid  = (batch + RPB - 1) / RPB;  // 1024 blocks
    ffm_fwd_kernel<<<grid, BLOCK, 0, stream>>>(dense, sparse, w0, w, v, out, batch);
}